// Round 12
// baseline (1090.480 us; speedup 1.0000x reference)
//
#include <hip/hip_runtime.h>
#include <hip/hip_fp16.h>

#define NPIX (512 * 512)
#define LOG2N 18         // NPIX == 2^18
#define NC 21
#define CP 12            // half2 pairs per padded row (24 halves, 48 B stride ->
                         // row starts always 0/16 mod 32 => every 44B payload gather
                         // spans exactly 2 sectors; CP=11 (44B stride) hit 3 sectors 25% of the time)
#define SCAN_CHUNK 2048
#define SCAN_T 256

static inline int cdiv_l(long a, int b) { return (int)((a + b - 1) / b); }

// ---------------- CSR build ----------------
// j-major traversal: t' in [0, K*N): j = t' >> LOG2N, n = t' & (N-1).
// hist + rank: atomic's return value is this entry's within-row rank (dense store).
__global__ void histrank2_k(const int* __restrict__ osA, int* __restrict__ cntA,
                            int* __restrict__ rnkA, int NA, int KA,
                            const int* __restrict__ osB, int* __restrict__ cntB,
                            int* __restrict__ rnkB, int NB, int KB) {
    int t = blockIdx.x * blockDim.x + threadIdx.x;
    if (t < NA) {
        int j = t >> LOG2N, n = t & (NPIX - 1);
        rnkA[t] = atomicAdd(&cntA[osA[(size_t)n * KA + j]], 1);
    } else {
        int tb = t - NA;
        if (tb < NB) {
            int j = tb >> LOG2N, n = tb & (NPIX - 1);
            rnkB[tb] = atomicAdd(&cntB[osB[(size_t)n * KB + j]], 1);
        }
    }
}

// dual-range scan stage 1: per-chunk sums for both lattices in one launch
__global__ void scan1d_k(const int* __restrict__ cntA, int* __restrict__ bsumA, int LA, int nbA,
                         const int* __restrict__ cntB, int* __restrict__ bsumB, int LB) {
    __shared__ int s[SCAN_T];
    int blk = blockIdx.x;
    const int* cnt; int* bsum; int L; int b;
    if (blk < nbA) { cnt = cntA; bsum = bsumA; L = LA; b = blk; }
    else           { cnt = cntB; bsum = bsumB; L = LB; b = blk - nbA; }
    int base = b * SCAN_CHUNK;
    int tsum = 0;
    for (int j = threadIdx.x; j < SCAN_CHUNK; j += SCAN_T) {
        int i = base + j;
        tsum += (i < L) ? cnt[i] : 0;
    }
    s[threadIdx.x] = tsum; __syncthreads();
    for (int o = SCAN_T / 2; o > 0; o >>= 1) {
        if (threadIdx.x < o) s[threadIdx.x] += s[threadIdx.x + o];
        __syncthreads();
    }
    if (threadIdx.x == 0) bsum[b] = s[0];
}

// dual scan stage 2: block 0 -> lattice A, block 1 -> lattice B
__global__ void scan2d_k(int* __restrict__ bsumA, int nbA, int* __restrict__ offA, int LA,
                         int* __restrict__ bsumB, int nbB, int* __restrict__ offB, int LB) {
    __shared__ int s[SCAN_T];
    int* bsum; int nb; int* off; int L;
    if (blockIdx.x == 0) { bsum = bsumA; nb = nbA; off = offA; L = LA; }
    else                 { bsum = bsumB; nb = nbB; off = offB; L = LB; }
    int tid = threadIdx.x;
    int per = (nb + SCAN_T - 1) / SCAN_T;
    int tsum = 0;
    for (int j = 0; j < per; j++) { int i = tid * per + j; if (i < nb) tsum += bsum[i]; }
    s[tid] = tsum; __syncthreads();
    for (int o = 1; o < SCAN_T; o <<= 1) {
        int v = (tid >= o) ? s[tid - o] : 0;
        __syncthreads();
        s[tid] += v;
        __syncthreads();
    }
    int excl = s[tid] - tsum;
    int total = s[SCAN_T - 1];
    int run = excl;
    for (int j = 0; j < per; j++) {
        int i = tid * per + j;
        if (i < nb) { int v = bsum[i]; bsum[i] = run; run += v; }
    }
    if (tid == 0) off[L] = total;
}

// dual scan stage 3: final exclusive scan
__global__ void scan3d_k(const int* __restrict__ cntA, const int* __restrict__ bsumA,
                         int* __restrict__ offA, int LA, int nbA,
                         const int* __restrict__ cntB, const int* __restrict__ bsumB,
                         int* __restrict__ offB, int LB) {
    __shared__ int s[SCAN_T];
    const int PER = SCAN_CHUNK / SCAN_T;  // 8
    int blk = blockIdx.x;
    const int* cnt; const int* bsum; int* off; int L; int b;
    if (blk < nbA) { cnt = cntA; bsum = bsumA; off = offA; L = LA; b = blk; }
    else           { cnt = cntB; bsum = bsumB; off = offB; L = LB; b = blk - nbA; }
    int tid = threadIdx.x;
    int base = b * SCAN_CHUNK + tid * PER;
    int c[PER];
    int tsum = 0;
#pragma unroll
    for (int j = 0; j < PER; j++) { int i = base + j; c[j] = (i < L) ? cnt[i] : 0; tsum += c[j]; }
    s[tid] = tsum; __syncthreads();
    for (int o = 1; o < SCAN_T; o <<= 1) {
        int v = (tid >= o) ? s[tid - o] : 0;
        __syncthreads();
        s[tid] += v;
        __syncthreads();
    }
    int run = bsum[b] + s[tid] - tsum;
#pragma unroll
    for (int j = 0; j < PER; j++) {
        int i = base + j;
        if (i < L) off[i] = run;
        run += c[j];
    }
}

// dual-range atomic-free scatter: p = off[m] + rnk[t]; one packed 8B store per entry
__global__ void scatter2_k(const int* __restrict__ osA, const float* __restrict__ wsA,
                           const int* __restrict__ offA, const int* __restrict__ rnkA,
                           int2* __restrict__ pA, int NA, int KA,
                           const int* __restrict__ osB, const float* __restrict__ wsB,
                           const int* __restrict__ offB, const int* __restrict__ rnkB,
                           int2* __restrict__ pB, int NB, int KB) {
    int t = blockIdx.x * blockDim.x + threadIdx.x;
    if (t < NA) {
        int j = t >> LOG2N, n = t & (NPIX - 1);
        size_t e = (size_t)n * KA + j;
        int m = osA[e];
        int p = offA[m] + rnkA[t];
        pA[p] = make_int2(n, __float_as_int(wsA[e]));
    } else {
        int tb = t - NA;
        if (tb < NB) {
            int j = tb >> LOG2N, n = tb & (NPIX - 1);
            size_t e = (size_t)n * KB + j;
            int m = osB[e];
            int p = offB[m] + rnkB[tb];
            pB[p] = make_int2(n, __float_as_int(wsB[e]));
        }
    }
}

// dual-range fold of nrm into packed entry weights (once per call)
__global__ void wn2_k(int2* __restrict__ pA, const float* __restrict__ nrmA, int NA,
                      int2* __restrict__ pB, const float* __restrict__ nrmB, int NB) {
    int t = blockIdx.x * blockDim.x + threadIdx.x;
    if (t < NA) {
        int2 e = pA[t];
        e.y = __float_as_int(__int_as_float(e.y) * nrmA[e.x]);
        pA[t] = e;
    } else {
        t -= NA;
        if (t < NB) {
            int2 e = pB[t];
            e.y = __float_as_int(__int_as_float(e.y) * nrmB[e.x]);
            pB[t] = e;
        }
    }
}

// ---------------- normalization lattice (C=1, f32), dual-range ----------------
__global__ void splat1d_k(const int2* __restrict__ pE_bi, const int* __restrict__ off_bi,
                          float* __restrict__ val_bi, int Mbi,
                          const int2* __restrict__ pE_sp, const int* __restrict__ off_sp,
                          float* __restrict__ val_sp, int Msp) {
    int t = blockIdx.x * blockDim.x + threadIdx.x;
    const int2* pE; const int* off; float* val; int m;
    if (t <= Mbi) { pE = pE_bi; off = off_bi; val = val_bi; m = t; }
    else {
        m = t - (Mbi + 1);
        if (m > Msp) return;
        pE = pE_sp; off = off_sp; val = val_sp;
    }
    float s = 0.f;
    if (m > 0) {
        int e0 = off[m], e1 = off[m + 1];
        for (int e = e0; e < e1; e++) s += __int_as_float(pE[e].y);
    }
    val[m] = s;
}

// dual blur sweep on f32 norm lattices; spIn==nullptr -> bilateral only
__global__ void blur1d_k(const float* __restrict__ biIn, float* __restrict__ biOut,
                         const int* __restrict__ nbr_bi, int Mbi,
                         const float* __restrict__ spIn, float* __restrict__ spOut,
                         const int* __restrict__ nbr_sp, int Msp) {
    int t = blockIdx.x * blockDim.x + threadIdx.x;
    if (t <= Mbi) {
        if (t == 0) { biOut[0] = 0.f; return; }
        int2 nn = ((const int2*)nbr_bi)[t - 1];
        biOut[t] = biIn[t] + 0.5f * (biIn[nn.x] + biIn[nn.y]);
    } else if (spIn) {
        int m = t - (Mbi + 1);
        if (m > Msp) return;
        if (m == 0) { spOut[0] = 0.f; return; }
        int2 nn = ((const int2*)nbr_sp)[m - 1];
        spOut[m] = spIn[m] + 0.5f * (spIn[nn.x] + spIn[nn.y]);
    }
}

// fused: slice_norm(bi) + slice_norm(sp) + softmax_init, per-pixel ranges
__global__ void prep_k(const float* __restrict__ unary,
                       const int* __restrict__ os_bi, const float* __restrict__ ws_bi,
                       const float* __restrict__ nv_bi, float* __restrict__ nrm_bi, float abi,
                       const int* __restrict__ os_sp, const float* __restrict__ ws_sp,
                       const float* __restrict__ nv_sp, float* __restrict__ nrm_sp, float asp,
                       __half2* __restrict__ Qh, __half2* __restrict__ uh, int N) {
    int t = blockIdx.x * blockDim.x + threadIdx.x;
    if (t < N) {
        float s = 0.f;
        for (int j = 0; j < 6; j++)
            s += ws_bi[(size_t)t * 6 + j] * nv_bi[os_bi[(size_t)t * 6 + j]];
        nrm_bi[t] = 1.f / (sqrtf(abi * s) + 1e-20f);
    } else if (t < 2 * N) {
        int n = t - N;
        float s = 0.f;
        for (int j = 0; j < 3; j++)
            s += ws_sp[(size_t)n * 3 + j] * nv_sp[os_sp[(size_t)n * 3 + j]];
        nrm_sp[n] = 1.f / (sqrtf(asp * s) + 1e-20f);
    } else if (t < 3 * N) {
        int n = t - 2 * N;
        const float* up = unary + (size_t)n * NC;
        float uv[2 * CP], v[2 * CP];
#pragma unroll
        for (int c = 0; c < 2 * CP; c++) { uv[c] = 0.f; v[c] = 0.f; }
        float mx = -1e30f;
#pragma unroll
        for (int c = 0; c < NC; c++) { uv[c] = up[c]; v[c] = -uv[c]; mx = fmaxf(mx, v[c]); }
        float s = 0.f;
#pragma unroll
        for (int c = 0; c < NC; c++) { v[c] = __expf(v[c] - mx); s += v[c]; }
        float inv = 1.f / s;
#pragma unroll
        for (int c = 0; c < NC; c++) v[c] *= inv;
        __half2* hp = Qh + (size_t)n * CP;
        __half2* uhp = uh + (size_t)n * CP;
#pragma unroll
        for (int i = 0; i < CP; i++) {
            hp[i]  = __floats2half2_rn(v[2 * i], v[2 * i + 1]);
            uhp[i] = __floats2half2_rn(uv[2 * i], uv[2 * i + 1]);
        }
    }
}

// ---------------- f16 lattice pipeline (thread per row) ----------------
// splat one lattice row from folded (n, w) entries
__device__ __forceinline__ void splat_row(const __half2* __restrict__ Qh,
                                          const int2* __restrict__ pE, const int* __restrict__ off,
                                          __half2* __restrict__ val, int m) {
    float acc[2 * CP];
#pragma unroll
    for (int i = 0; i < 2 * CP; i++) acc[i] = 0.f;
    if (m > 0) {
        int e0 = off[m], e1 = off[m + 1];
        for (int e = e0; e < e1; e++) {
            int2 ent = pE[e];
            float w = __int_as_float(ent.y);
            const __half2* qp = Qh + (size_t)ent.x * CP;
#pragma unroll
            for (int i = 0; i < CP; i++) {
                float2 q = __half22float2(qp[i]);
                acc[2 * i]     += w * q.x;
                acc[2 * i + 1] += w * q.y;
            }
        }
    }
    __half2* vp = val + (size_t)m * CP;
#pragma unroll
    for (int i = 0; i < CP; i++)
        vp[i] = __floats2half2_rn(acc[2 * i], acc[2 * i + 1]);
}

// dual-range splat (bilateral rows then spatial rows)
__global__ void splatH2_k(const __half2* __restrict__ Qh,
                          const int2* __restrict__ pE_bi, const int* __restrict__ off_bi,
                          __half2* __restrict__ val_bi, int Mbi,
                          const int2* __restrict__ pE_sp, const int* __restrict__ off_sp,
                          __half2* __restrict__ val_sp, int Msp) {
    int t = blockIdx.x * blockDim.x + threadIdx.x;
    if (t <= Mbi) {
        splat_row(Qh, pE_bi, off_bi, val_bi, t);
    } else {
        int m = t - (Mbi + 1);
        if (m > Msp) return;
        splat_row(Qh, pE_sp, off_sp, val_sp, m);
    }
}

// row helpers for blur
__device__ __forceinline__ void blur2_row(const __half2* __restrict__ vin, __half2* __restrict__ op,
                                          const int* __restrict__ nbrA, const int* __restrict__ nbrB,
                                          int m) {
    if (m == 0) {
        __half2 z = __floats2half2_rn(0.f, 0.f);
#pragma unroll
        for (int i = 0; i < CP; i++) op[i] = z;
        return;
    }
    float acc[2 * CP];
#pragma unroll
    for (int i = 0; i < 2 * CP; i++) acc[i] = 0.f;
    int2 nbB = ((const int2*)nbrB)[m - 1];
    {
        int2 na = ((const int2*)nbrA)[m - 1];
        const __half2* p0 = vin + (size_t)m * CP;
        const __half2* p1 = vin + (size_t)na.x * CP;
        const __half2* p2 = vin + (size_t)na.y * CP;
#pragma unroll
        for (int i = 0; i < CP; i++) {
            float2 a = __half22float2(p0[i]);
            float2 b = __half22float2(p1[i]);
            float2 c = __half22float2(p2[i]);
            acc[2 * i]     += a.x + 0.5f * (b.x + c.x);
            acc[2 * i + 1] += a.y + 0.5f * (b.y + c.y);
        }
    }
    if (nbB.x > 0) {
        int2 na = ((const int2*)nbrA)[nbB.x - 1];
        const __half2* p0 = vin + (size_t)nbB.x * CP;
        const __half2* p1 = vin + (size_t)na.x * CP;
        const __half2* p2 = vin + (size_t)na.y * CP;
#pragma unroll
        for (int i = 0; i < CP; i++) {
            float2 a = __half22float2(p0[i]);
            float2 b = __half22float2(p1[i]);
            float2 c = __half22float2(p2[i]);
            acc[2 * i]     += 0.5f * (a.x + 0.5f * (b.x + c.x));
            acc[2 * i + 1] += 0.5f * (a.y + 0.5f * (b.y + c.y));
        }
    }
    if (nbB.y > 0) {
        int2 na = ((const int2*)nbrA)[nbB.y - 1];
        const __half2* p0 = vin + (size_t)nbB.y * CP;
        const __half2* p1 = vin + (size_t)na.x * CP;
        const __half2* p2 = vin + (size_t)na.y * CP;
#pragma unroll
        for (int i = 0; i < CP; i++) {
            float2 a = __half22float2(p0[i]);
            float2 b = __half22float2(p1[i]);
            float2 c = __half22float2(p2[i]);
            acc[2 * i]     += 0.5f * (a.x + 0.5f * (b.x + c.x));
            acc[2 * i + 1] += 0.5f * (a.y + 0.5f * (b.y + c.y));
        }
    }
#pragma unroll
    for (int i = 0; i < CP; i++)
        op[i] = __floats2half2_rn(acc[2 * i], acc[2 * i + 1]);
}

__device__ __forceinline__ void blur1_row(const __half2* __restrict__ vin, __half2* __restrict__ op,
                                          const int* __restrict__ nbr, int m) {
    if (m == 0) {
        __half2 z = __floats2half2_rn(0.f, 0.f);
#pragma unroll
        for (int i = 0; i < CP; i++) op[i] = z;
        return;
    }
    int2 nn = ((const int2*)nbr)[m - 1];
    const __half2* p0 = vin + (size_t)m * CP;
    const __half2* p1 = vin + (size_t)nn.x * CP;
    const __half2* p2 = vin + (size_t)nn.y * CP;
#pragma unroll
    for (int i = 0; i < CP; i++) {
        float2 a = __half22float2(p0[i]);
        float2 b = __half22float2(p1[i]);
        float2 c = __half22float2(p2[i]);
        op[i] = __floats2half2_rn(a.x + 0.5f * (b.x + c.x), a.y + 0.5f * (b.y + c.y));
    }
}

// phase 1: bilateral double-blur + spatial double-blur
__global__ void blurP1_k(const __half2* __restrict__ biIn, __half2* __restrict__ biOut,
                         const int* __restrict__ nA_bi, const int* __restrict__ nB_bi, int Mbi,
                         const __half2* __restrict__ spIn, __half2* __restrict__ spOut,
                         const int* __restrict__ nA_sp, const int* __restrict__ nB_sp, int Msp) {
    int t = blockIdx.x * blockDim.x + threadIdx.x;
    if (t <= Mbi) {
        blur2_row(biIn, biOut + (size_t)t * CP, nA_bi, nB_bi, t);
    } else {
        int m = t - (Mbi + 1);
        if (m > Msp) return;
        blur2_row(spIn, spOut + (size_t)m * CP, nA_sp, nB_sp, m);
    }
}

// phase 2: bilateral double-blur + spatial single-blur
__global__ void blurP2_k(const __half2* __restrict__ biIn, __half2* __restrict__ biOut,
                         const int* __restrict__ nA_bi, const int* __restrict__ nB_bi, int Mbi,
                         const __half2* __restrict__ spIn, __half2* __restrict__ spOut,
                         const int* __restrict__ nA_sp, int Msp) {
    int t = blockIdx.x * blockDim.x + threadIdx.x;
    if (t <= Mbi) {
        blur2_row(biIn, biOut + (size_t)t * CP, nA_bi, nB_bi, t);
    } else {
        int m = t - (Mbi + 1);
        if (m > Msp) return;
        blur1_row(spIn, spOut + (size_t)m * CP, nA_sp, m);
    }
}

// phase 3: bilateral double-blur only
__global__ void blurP3_k(const __half2* __restrict__ biIn, __half2* __restrict__ biOut,
                         const int* __restrict__ nA_bi, const int* __restrict__ nB_bi, int Mbi) {
    int t = blockIdx.x * blockDim.x + threadIdx.x;
    if (t > Mbi) return;
    blur2_row(biIn, biOut + (size_t)t * CP, nA_bi, nB_bi, t);
}

// fused: slice bilateral + slice spatial + softmax update.
__global__ void slice_update_k(const __half2* __restrict__ uh,
                               const int* __restrict__ os_bi, const float* __restrict__ ws_bi,
                               const __half2* __restrict__ vbi, const float* __restrict__ nrm_bi,
                               const int* __restrict__ os_sp, const float* __restrict__ ws_sp,
                               const __half2* __restrict__ vsp, const float* __restrict__ nrm_sp,
                               float* __restrict__ Q, __half2* __restrict__ Qh,
                               int N, float abi, float asp, int final_it) {
    int n = blockIdx.x * blockDim.x + threadIdx.x;
    if (n >= N) return;
    float acc[2 * CP];
#pragma unroll
    for (int i = 0; i < 2 * CP; i++) acc[i] = 0.f;
    for (int j = 0; j < 6; j++) {
        float w = ws_bi[(size_t)n * 6 + j];
        const __half2* vp = vbi + (size_t)os_bi[(size_t)n * 6 + j] * CP;
#pragma unroll
        for (int i = 0; i < CP; i++) {
            float2 f = __half22float2(vp[i]);
            acc[2 * i]     += w * f.x;
            acc[2 * i + 1] += w * f.y;
        }
    }
    float sb = 10.f * abi * nrm_bi[n];
#pragma unroll
    for (int i = 0; i < 2 * CP; i++) acc[i] *= sb;
    float ss = 3.f * asp * nrm_sp[n];
    for (int j = 0; j < 3; j++) {
        float w = ss * ws_sp[(size_t)n * 3 + j];
        const __half2* vp = vsp + (size_t)os_sp[(size_t)n * 3 + j] * CP;
#pragma unroll
        for (int i = 0; i < CP; i++) {
            float2 f = __half22float2(vp[i]);
            acc[2 * i]     += w * f.x;
            acc[2 * i + 1] += w * f.y;
        }
    }
    const __half2* uhp = uh + (size_t)n * CP;
#pragma unroll
    for (int i = 0; i < CP; i++) {
        float2 uu = __half22float2(uhp[i]);
        acc[2 * i]     -= uu.x;
        acc[2 * i + 1] -= uu.y;
    }
    float mx = -1e30f;
#pragma unroll
    for (int c = 0; c < NC; c++) mx = fmaxf(mx, acc[c]);
    float s = 0.f;
#pragma unroll
    for (int c = 0; c < NC; c++) { acc[c] = __expf(acc[c] - mx); s += acc[c]; }
    float inv = 1.f / s;
#pragma unroll
    for (int c = 0; c < NC; c++) acc[c] *= inv;
#pragma unroll
    for (int c = NC; c < 2 * CP; c++) acc[c] = 0.f;
    if (final_it) {
        float* qp = Q + (size_t)n * NC;
#pragma unroll
        for (int c = 0; c < NC; c++) qp[c] = acc[c];
    } else {
        __half2* hp = Qh + (size_t)n * CP;
#pragma unroll
        for (int i = 0; i < CP; i++) hp[i] = __floats2half2_rn(acc[2 * i], acc[2 * i + 1]);
    }
}

extern "C" void kernel_launch(void* const* d_in, const int* in_sizes, int n_in,
                              void* d_out, int out_size, void* d_ws, size_t ws_size,
                              hipStream_t stream) {
    const float* unary  = (const float*)d_in[0];
    const float* ws_bi  = (const float*)d_in[1];
    const float* ws_sp  = (const float*)d_in[2];
    const int*   os_bi  = (const int*)d_in[3];
    const int*   os_sp  = (const int*)d_in[4];
    const int*   nbr_bi = (const int*)d_in[5];
    const int*   nbr_sp = (const int*)d_in[6];
    float* Q = (float*)d_out;

    const int N = NPIX, Kbi = 6, Ksp = 3;
    const int Mbi = in_sizes[5] / (Kbi * 2);
    const int Msp = in_sizes[6] / (Ksp * 2);
    const int NKbi = N * Kbi, NKsp = N * Ksp;
    const float alpha_bi = 32.f / 33.f;
    const float alpha_sp = 0.8f;

    // ---- workspace layout (4-byte units) ----
    char* basec = (char*)d_ws;
    size_t off4 = 0;
    auto allocf = [&](size_t nf) { float* p = (float*)basec + off4; off4 += (nf + 3) & ~(size_t)3; return p; };
    auto alloci = [&](size_t ni) { int* p = (int*)basec + off4; off4 += (ni + 3) & ~(size_t)3; return p; };
    auto alloch2 = [&](size_t nh2) { __half2* p = (__half2*)((float*)basec + off4); off4 += (nh2 + 3) & ~(size_t)3; return p; };
    auto alloci2 = [&](size_t ni2) { int2* p = (int2*)((float*)basec + off4); off4 += 2 * ni2; return p; };

    float*   nrm_bi = allocf(N);
    float*   nrm_sp = allocf(N);
    __half2* Qh     = alloch2((size_t)N * CP);
    __half2* uh     = alloch2((size_t)N * CP);
    int2*    pE_bi  = alloci2(NKbi);
    int*     off_bi = alloci(Mbi + 2);
    int2*    pE_sp  = alloci2(NKsp);
    int*     off_sp = alloci(Msp + 2);
    int*     bsumA  = alloci(4096);
    int*     bsumB  = alloci(4096);
    __half2* vbiA   = alloch2((size_t)(Mbi + 1) * CP);
    __half2* vbiB   = alloch2((size_t)(Mbi + 1) * CP);
    __half2* vspA   = alloch2((size_t)(Msp + 1) * CP);
    __half2* vspB   = alloch2((size_t)(Msp + 1) * CP);
    // cnt/rnk are only live during the CSR build (before splat1d), so they alias
    // the vbiA region (first use of vbiA is nv_biA in splat1d, after scatter2).
    int* cnt_bi = (int*)vbiA;
    int* cnt_sp = cnt_bi + (Mbi + 1);
    int* rnk_bi = cnt_sp + (Msp + 1);
    int* rnk_sp = rnk_bi + NKbi;
    // f32 norm-lattice buffers reuse the (not-yet-live) f16 value regions
    float* nv_biA = (float*)vbiA;
    float* nv_biB = (float*)vbiB;
    float* nv_spA = (float*)vspA;
    float* nv_spB = (float*)vspB;

    const int B = 256;
    const int nb_bi = cdiv_l(Mbi + 1, SCAN_CHUNK);
    const int nb_sp = cdiv_l(Msp + 1, SCAN_CHUNK);
    const size_t cnt_span = ((size_t)(Mbi + 1) + (Msp + 1)) * sizeof(int);
    const int rows2 = (Mbi + 1) + (Msp + 1);

    // ---- CSR build (both lattices), j-major, rank-trick (atomic-free scatter) ----
    hipMemsetAsync(cnt_bi, 0, cnt_span, stream);
    histrank2_k<<<cdiv_l((long)NKbi + NKsp, B), B, 0, stream>>>(
        os_bi, cnt_bi, rnk_bi, NKbi, Kbi, os_sp, cnt_sp, rnk_sp, NKsp, Ksp);
    scan1d_k<<<nb_bi + nb_sp, SCAN_T, 0, stream>>>(cnt_bi, bsumA, Mbi + 1, nb_bi,
                                                   cnt_sp, bsumB, Msp + 1);
    scan2d_k<<<2, SCAN_T, 0, stream>>>(bsumA, nb_bi, off_bi, Mbi + 1,
                                       bsumB, nb_sp, off_sp, Msp + 1);
    scan3d_k<<<nb_bi + nb_sp, SCAN_T, 0, stream>>>(cnt_bi, bsumA, off_bi, Mbi + 1, nb_bi,
                                                   cnt_sp, bsumB, off_sp, Msp + 1);
    scatter2_k<<<cdiv_l((long)NKbi + NKsp, B), B, 0, stream>>>(
        os_bi, ws_bi, off_bi, rnk_bi, pE_bi, NKbi, Kbi,
        os_sp, ws_sp, off_sp, rnk_sp, pE_sp, NKsp, Ksp);

    // ---- normalization lattices (C=1, f32), dual-range ----
    splat1d_k<<<cdiv_l(rows2, B), B, 0, stream>>>(pE_bi, off_bi, nv_biA, Mbi,
                                                  pE_sp, off_sp, nv_spA, Msp);
    {
        float* sb = nv_biA; float* db = nv_biB;
        float* sp = nv_spA; float* dp = nv_spB;
        for (int j = 0; j < 3; j++) {   // dual sweeps (bi dir j, sp dir j)
            blur1d_k<<<cdiv_l(rows2, B), B, 0, stream>>>(
                sb, db, nbr_bi + (size_t)j * Mbi * 2, Mbi,
                sp, dp, nbr_sp + (size_t)j * Msp * 2, Msp);
            float* t = sb; sb = db; db = t;
            t = sp; sp = dp; dp = t;
        }
        for (int j = 3; j < 6; j++) {   // bilateral-only sweeps
            blur1d_k<<<cdiv_l(Mbi + 1, B), B, 0, stream>>>(
                sb, db, nbr_bi + (size_t)j * Mbi * 2, Mbi,
                nullptr, nullptr, nullptr, 0);
            float* t = sb; sb = db; db = t;
        }
        prep_k<<<cdiv_l(3L * N, B), B, 0, stream>>>(
            unary, os_bi, ws_bi, sb, nrm_bi, alpha_bi,
            os_sp, ws_sp, sp, nrm_sp, alpha_sp, Qh, uh, N);
    }

    // ---- fold nrm into packed entry weights ----
    wn2_k<<<cdiv_l((long)NKbi + NKsp, B), B, 0, stream>>>(pE_bi, nrm_bi, NKbi, pE_sp, nrm_sp, NKsp);

    // ---- mean-field iterations ----
    for (int it = 0; it < 5; it++) {
        splatH2_k<<<cdiv_l(rows2, B), B, 0, stream>>>(
            Qh, pE_bi, off_bi, vbiA, Mbi,
            pE_sp, off_sp, vspA, Msp);
        blurP1_k<<<cdiv_l(rows2, B), B, 0, stream>>>(
            vbiA, vbiB, nbr_bi + (size_t)0 * Mbi * 2, nbr_bi + (size_t)1 * Mbi * 2, Mbi,
            vspA, vspB, nbr_sp + (size_t)0 * Msp * 2, nbr_sp + (size_t)1 * Msp * 2, Msp);
        blurP2_k<<<cdiv_l(rows2, B), B, 0, stream>>>(
            vbiB, vbiA, nbr_bi + (size_t)2 * Mbi * 2, nbr_bi + (size_t)3 * Mbi * 2, Mbi,
            vspB, vspA, nbr_sp + (size_t)2 * Msp * 2, Msp);
        blurP3_k<<<cdiv_l(Mbi + 1, B), B, 0, stream>>>(
            vbiA, vbiB, nbr_bi + (size_t)4 * Mbi * 2, nbr_bi + (size_t)5 * Mbi * 2, Mbi);
        slice_update_k<<<cdiv_l(N, B), B, 0, stream>>>(
            uh, os_bi, ws_bi, vbiB, nrm_bi, os_sp, ws_sp, vspA, nrm_sp,
            Q, Qh, N, alpha_bi, alpha_sp, it == 4 ? 1 : 0);
    }
}

// Round 13
// 1069.887 us; speedup vs baseline: 1.0192x; 1.0192x over previous
//
#include <hip/hip_runtime.h>
#include <hip/hip_fp16.h>

#define NPIX (512 * 512)
#define LOG2N 18         // NPIX == 2^18
#define NC 21
#define CP 11            // half2 pairs per padded row (22 halves, 44 B)
                         // NOTE: CP=12 (48B, sector-aligned) measured NEUTRAL-negative (R11):
                         // gathers are L2/L3-line served; dense +9% footprint cancels alignment.
#define SCAN_CHUNK 2048
#define SCAN_T 256

static inline int cdiv_l(long a, int b) { return (int)((a + b - 1) / b); }

// ---------------- CSR build ----------------
// j-major traversal: t' in [0, K*N): j = t' >> LOG2N, n = t' & (N-1).
// hist + rank: atomic's return value is this entry's within-row rank (dense store).
__global__ void histrank2_k(const int* __restrict__ osA, int* __restrict__ cntA,
                            int* __restrict__ rnkA, int NA, int KA,
                            const int* __restrict__ osB, int* __restrict__ cntB,
                            int* __restrict__ rnkB, int NB, int KB) {
    int t = blockIdx.x * blockDim.x + threadIdx.x;
    if (t < NA) {
        int j = t >> LOG2N, n = t & (NPIX - 1);
        rnkA[t] = atomicAdd(&cntA[osA[(size_t)n * KA + j]], 1);
    } else {
        int tb = t - NA;
        if (tb < NB) {
            int j = tb >> LOG2N, n = tb & (NPIX - 1);
            rnkB[tb] = atomicAdd(&cntB[osB[(size_t)n * KB + j]], 1);
        }
    }
}

// dual-range scan stage 1: per-chunk sums for both lattices in one launch
__global__ void scan1d_k(const int* __restrict__ cntA, int* __restrict__ bsumA, int LA, int nbA,
                         const int* __restrict__ cntB, int* __restrict__ bsumB, int LB) {
    __shared__ int s[SCAN_T];
    int blk = blockIdx.x;
    const int* cnt; int* bsum; int L; int b;
    if (blk < nbA) { cnt = cntA; bsum = bsumA; L = LA; b = blk; }
    else           { cnt = cntB; bsum = bsumB; L = LB; b = blk - nbA; }
    int base = b * SCAN_CHUNK;
    int tsum = 0;
    for (int j = threadIdx.x; j < SCAN_CHUNK; j += SCAN_T) {
        int i = base + j;
        tsum += (i < L) ? cnt[i] : 0;
    }
    s[threadIdx.x] = tsum; __syncthreads();
    for (int o = SCAN_T / 2; o > 0; o >>= 1) {
        if (threadIdx.x < o) s[threadIdx.x] += s[threadIdx.x + o];
        __syncthreads();
    }
    if (threadIdx.x == 0) bsum[b] = s[0];
}

// dual scan stage 2: block 0 -> lattice A, block 1 -> lattice B
__global__ void scan2d_k(int* __restrict__ bsumA, int nbA, int* __restrict__ offA, int LA,
                         int* __restrict__ bsumB, int nbB, int* __restrict__ offB, int LB) {
    __shared__ int s[SCAN_T];
    int* bsum; int nb; int* off; int L;
    if (blockIdx.x == 0) { bsum = bsumA; nb = nbA; off = offA; L = LA; }
    else                 { bsum = bsumB; nb = nbB; off = offB; L = LB; }
    int tid = threadIdx.x;
    int per = (nb + SCAN_T - 1) / SCAN_T;
    int tsum = 0;
    for (int j = 0; j < per; j++) { int i = tid * per + j; if (i < nb) tsum += bsum[i]; }
    s[tid] = tsum; __syncthreads();
    for (int o = 1; o < SCAN_T; o <<= 1) {
        int v = (tid >= o) ? s[tid - o] : 0;
        __syncthreads();
        s[tid] += v;
        __syncthreads();
    }
    int excl = s[tid] - tsum;
    int total = s[SCAN_T - 1];
    int run = excl;
    for (int j = 0; j < per; j++) {
        int i = tid * per + j;
        if (i < nb) { int v = bsum[i]; bsum[i] = run; run += v; }
    }
    if (tid == 0) off[L] = total;
}

// dual scan stage 3: final exclusive scan
__global__ void scan3d_k(const int* __restrict__ cntA, const int* __restrict__ bsumA,
                         int* __restrict__ offA, int LA, int nbA,
                         const int* __restrict__ cntB, const int* __restrict__ bsumB,
                         int* __restrict__ offB, int LB) {
    __shared__ int s[SCAN_T];
    const int PER = SCAN_CHUNK / SCAN_T;  // 8
    int blk = blockIdx.x;
    const int* cnt; const int* bsum; int* off; int L; int b;
    if (blk < nbA) { cnt = cntA; bsum = bsumA; off = offA; L = LA; b = blk; }
    else           { cnt = cntB; bsum = bsumB; off = offB; L = LB; b = blk - nbA; }
    int tid = threadIdx.x;
    int base = b * SCAN_CHUNK + tid * PER;
    int c[PER];
    int tsum = 0;
#pragma unroll
    for (int j = 0; j < PER; j++) { int i = base + j; c[j] = (i < L) ? cnt[i] : 0; tsum += c[j]; }
    s[tid] = tsum; __syncthreads();
    for (int o = 1; o < SCAN_T; o <<= 1) {
        int v = (tid >= o) ? s[tid - o] : 0;
        __syncthreads();
        s[tid] += v;
        __syncthreads();
    }
    int run = bsum[b] + s[tid] - tsum;
#pragma unroll
    for (int j = 0; j < PER; j++) {
        int i = base + j;
        if (i < L) off[i] = run;
        run += c[j];
    }
}

// dual-range atomic-free scatter: p = off[m] + rnk[t]; one packed 8B store per entry
__global__ void scatter2_k(const int* __restrict__ osA, const float* __restrict__ wsA,
                           const int* __restrict__ offA, const int* __restrict__ rnkA,
                           int2* __restrict__ pA, int NA, int KA,
                           const int* __restrict__ osB, const float* __restrict__ wsB,
                           const int* __restrict__ offB, const int* __restrict__ rnkB,
                           int2* __restrict__ pB, int NB, int KB) {
    int t = blockIdx.x * blockDim.x + threadIdx.x;
    if (t < NA) {
        int j = t >> LOG2N, n = t & (NPIX - 1);
        size_t e = (size_t)n * KA + j;
        int m = osA[e];
        int p = offA[m] + rnkA[t];
        pA[p] = make_int2(n, __float_as_int(wsA[e]));
    } else {
        int tb = t - NA;
        if (tb < NB) {
            int j = tb >> LOG2N, n = tb & (NPIX - 1);
            size_t e = (size_t)n * KB + j;
            int m = osB[e];
            int p = offB[m] + rnkB[tb];
            pB[p] = make_int2(n, __float_as_int(wsB[e]));
        }
    }
}

// dual-range fold of nrm into packed entry weights (once per call)
__global__ void wn2_k(int2* __restrict__ pA, const float* __restrict__ nrmA, int NA,
                      int2* __restrict__ pB, const float* __restrict__ nrmB, int NB) {
    int t = blockIdx.x * blockDim.x + threadIdx.x;
    if (t < NA) {
        int2 e = pA[t];
        e.y = __float_as_int(__int_as_float(e.y) * nrmA[e.x]);
        pA[t] = e;
    } else {
        t -= NA;
        if (t < NB) {
            int2 e = pB[t];
            e.y = __float_as_int(__int_as_float(e.y) * nrmB[e.x]);
            pB[t] = e;
        }
    }
}

// ---------------- normalization lattice (C=1, f32), dual-range ----------------
__global__ void splat1d_k(const int2* __restrict__ pE_bi, const int* __restrict__ off_bi,
                          float* __restrict__ val_bi, int Mbi,
                          const int2* __restrict__ pE_sp, const int* __restrict__ off_sp,
                          float* __restrict__ val_sp, int Msp) {
    int t = blockIdx.x * blockDim.x + threadIdx.x;
    const int2* pE; const int* off; float* val; int m;
    if (t <= Mbi) { pE = pE_bi; off = off_bi; val = val_bi; m = t; }
    else {
        m = t - (Mbi + 1);
        if (m > Msp) return;
        pE = pE_sp; off = off_sp; val = val_sp;
    }
    float s = 0.f;
    if (m > 0) {
        int e0 = off[m], e1 = off[m + 1];
        for (int e = e0; e < e1; e++) s += __int_as_float(pE[e].y);
    }
    val[m] = s;
}

// dual blur sweep on f32 norm lattices; spIn==nullptr -> bilateral only
__global__ void blur1d_k(const float* __restrict__ biIn, float* __restrict__ biOut,
                         const int* __restrict__ nbr_bi, int Mbi,
                         const float* __restrict__ spIn, float* __restrict__ spOut,
                         const int* __restrict__ nbr_sp, int Msp) {
    int t = blockIdx.x * blockDim.x + threadIdx.x;
    if (t <= Mbi) {
        if (t == 0) { biOut[0] = 0.f; return; }
        int2 nn = ((const int2*)nbr_bi)[t - 1];
        biOut[t] = biIn[t] + 0.5f * (biIn[nn.x] + biIn[nn.y]);
    } else if (spIn) {
        int m = t - (Mbi + 1);
        if (m > Msp) return;
        if (m == 0) { spOut[0] = 0.f; return; }
        int2 nn = ((const int2*)nbr_sp)[m - 1];
        spOut[m] = spIn[m] + 0.5f * (spIn[nn.x] + spIn[nn.y]);
    }
}

// fused: slice_norm(bi) + slice_norm(sp) + softmax_init, per-pixel ranges
__global__ void prep_k(const float* __restrict__ unary,
                       const int* __restrict__ os_bi, const float* __restrict__ ws_bi,
                       const float* __restrict__ nv_bi, float* __restrict__ nrm_bi, float abi,
                       const int* __restrict__ os_sp, const float* __restrict__ ws_sp,
                       const float* __restrict__ nv_sp, float* __restrict__ nrm_sp, float asp,
                       __half2* __restrict__ Qh, __half2* __restrict__ uh, int N) {
    int t = blockIdx.x * blockDim.x + threadIdx.x;
    if (t < N) {
        float s = 0.f;
        for (int j = 0; j < 6; j++)
            s += ws_bi[(size_t)t * 6 + j] * nv_bi[os_bi[(size_t)t * 6 + j]];
        nrm_bi[t] = 1.f / (sqrtf(abi * s) + 1e-20f);
    } else if (t < 2 * N) {
        int n = t - N;
        float s = 0.f;
        for (int j = 0; j < 3; j++)
            s += ws_sp[(size_t)n * 3 + j] * nv_sp[os_sp[(size_t)n * 3 + j]];
        nrm_sp[n] = 1.f / (sqrtf(asp * s) + 1e-20f);
    } else if (t < 3 * N) {
        int n = t - 2 * N;
        const float* up = unary + (size_t)n * NC;
        float uv[2 * CP], v[2 * CP];
#pragma unroll
        for (int c = 0; c < 2 * CP; c++) { uv[c] = 0.f; v[c] = 0.f; }
        float mx = -1e30f;
#pragma unroll
        for (int c = 0; c < NC; c++) { uv[c] = up[c]; v[c] = -uv[c]; mx = fmaxf(mx, v[c]); }
        float s = 0.f;
#pragma unroll
        for (int c = 0; c < NC; c++) { v[c] = __expf(v[c] - mx); s += v[c]; }
        float inv = 1.f / s;
#pragma unroll
        for (int c = 0; c < NC; c++) v[c] *= inv;
        v[NC] = 0.f;
        __half2* hp = Qh + (size_t)n * CP;
        __half2* uhp = uh + (size_t)n * CP;
#pragma unroll
        for (int i = 0; i < CP; i++) {
            hp[i]  = __floats2half2_rn(v[2 * i], v[2 * i + 1]);
            uhp[i] = __floats2half2_rn(uv[2 * i], uv[2 * i + 1]);
        }
    }
}

// ---------------- f16 lattice pipeline (thread per row) ----------------
// splat one lattice row from folded (n, w) entries
__device__ __forceinline__ void splat_row(const __half2* __restrict__ Qh,
                                          const int2* __restrict__ pE, const int* __restrict__ off,
                                          __half2* __restrict__ val, int m) {
    float acc[2 * CP];
#pragma unroll
    for (int i = 0; i < 2 * CP; i++) acc[i] = 0.f;
    if (m > 0) {
        int e0 = off[m], e1 = off[m + 1];
        for (int e = e0; e < e1; e++) {
            int2 ent = pE[e];
            float w = __int_as_float(ent.y);
            const __half2* qp = Qh + (size_t)ent.x * CP;
#pragma unroll
            for (int i = 0; i < CP; i++) {
                float2 q = __half22float2(qp[i]);
                acc[2 * i]     += w * q.x;
                acc[2 * i + 1] += w * q.y;
            }
        }
    }
    __half2* vp = val + (size_t)m * CP;
#pragma unroll
    for (int i = 0; i < CP; i++)
        vp[i] = __floats2half2_rn(acc[2 * i], acc[2 * i + 1]);
}

// dual-range splat (bilateral rows then spatial rows)
__global__ void splatH2_k(const __half2* __restrict__ Qh,
                          const int2* __restrict__ pE_bi, const int* __restrict__ off_bi,
                          __half2* __restrict__ val_bi, int Mbi,
                          const int2* __restrict__ pE_sp, const int* __restrict__ off_sp,
                          __half2* __restrict__ val_sp, int Msp) {
    int t = blockIdx.x * blockDim.x + threadIdx.x;
    if (t <= Mbi) {
        splat_row(Qh, pE_bi, off_bi, val_bi, t);
    } else {
        int m = t - (Mbi + 1);
        if (m > Msp) return;
        splat_row(Qh, pE_sp, off_sp, val_sp, m);
    }
}

// row helpers for blur
__device__ __forceinline__ void blur2_row(const __half2* __restrict__ vin, __half2* __restrict__ op,
                                          const int* __restrict__ nbrA, const int* __restrict__ nbrB,
                                          int m) {
    if (m == 0) {
        __half2 z = __floats2half2_rn(0.f, 0.f);
#pragma unroll
        for (int i = 0; i < CP; i++) op[i] = z;
        return;
    }
    float acc[2 * CP];
#pragma unroll
    for (int i = 0; i < 2 * CP; i++) acc[i] = 0.f;
    int2 nbB = ((const int2*)nbrB)[m - 1];
    {
        int2 na = ((const int2*)nbrA)[m - 1];
        const __half2* p0 = vin + (size_t)m * CP;
        const __half2* p1 = vin + (size_t)na.x * CP;
        const __half2* p2 = vin + (size_t)na.y * CP;
#pragma unroll
        for (int i = 0; i < CP; i++) {
            float2 a = __half22float2(p0[i]);
            float2 b = __half22float2(p1[i]);
            float2 c = __half22float2(p2[i]);
            acc[2 * i]     += a.x + 0.5f * (b.x + c.x);
            acc[2 * i + 1] += a.y + 0.5f * (b.y + c.y);
        }
    }
    if (nbB.x > 0) {
        int2 na = ((const int2*)nbrA)[nbB.x - 1];
        const __half2* p0 = vin + (size_t)nbB.x * CP;
        const __half2* p1 = vin + (size_t)na.x * CP;
        const __half2* p2 = vin + (size_t)na.y * CP;
#pragma unroll
        for (int i = 0; i < CP; i++) {
            float2 a = __half22float2(p0[i]);
            float2 b = __half22float2(p1[i]);
            float2 c = __half22float2(p2[i]);
            acc[2 * i]     += 0.5f * (a.x + 0.5f * (b.x + c.x));
            acc[2 * i + 1] += 0.5f * (a.y + 0.5f * (b.y + c.y));
        }
    }
    if (nbB.y > 0) {
        int2 na = ((const int2*)nbrA)[nbB.y - 1];
        const __half2* p0 = vin + (size_t)nbB.y * CP;
        const __half2* p1 = vin + (size_t)na.x * CP;
        const __half2* p2 = vin + (size_t)na.y * CP;
#pragma unroll
        for (int i = 0; i < CP; i++) {
            float2 a = __half22float2(p0[i]);
            float2 b = __half22float2(p1[i]);
            float2 c = __half22float2(p2[i]);
            acc[2 * i]     += 0.5f * (a.x + 0.5f * (b.x + c.x));
            acc[2 * i + 1] += 0.5f * (a.y + 0.5f * (b.y + c.y));
        }
    }
#pragma unroll
    for (int i = 0; i < CP; i++)
        op[i] = __floats2half2_rn(acc[2 * i], acc[2 * i + 1]);
}

__device__ __forceinline__ void blur1_row(const __half2* __restrict__ vin, __half2* __restrict__ op,
                                          const int* __restrict__ nbr, int m) {
    if (m == 0) {
        __half2 z = __floats2half2_rn(0.f, 0.f);
#pragma unroll
        for (int i = 0; i < CP; i++) op[i] = z;
        return;
    }
    int2 nn = ((const int2*)nbr)[m - 1];
    const __half2* p0 = vin + (size_t)m * CP;
    const __half2* p1 = vin + (size_t)nn.x * CP;
    const __half2* p2 = vin + (size_t)nn.y * CP;
#pragma unroll
    for (int i = 0; i < CP; i++) {
        float2 a = __half22float2(p0[i]);
        float2 b = __half22float2(p1[i]);
        float2 c = __half22float2(p2[i]);
        op[i] = __floats2half2_rn(a.x + 0.5f * (b.x + c.x), a.y + 0.5f * (b.y + c.y));
    }
}

// phase 1: bilateral double-blur + spatial double-blur
__global__ void blurP1_k(const __half2* __restrict__ biIn, __half2* __restrict__ biOut,
                         const int* __restrict__ nA_bi, const int* __restrict__ nB_bi, int Mbi,
                         const __half2* __restrict__ spIn, __half2* __restrict__ spOut,
                         const int* __restrict__ nA_sp, const int* __restrict__ nB_sp, int Msp) {
    int t = blockIdx.x * blockDim.x + threadIdx.x;
    if (t <= Mbi) {
        blur2_row(biIn, biOut + (size_t)t * CP, nA_bi, nB_bi, t);
    } else {
        int m = t - (Mbi + 1);
        if (m > Msp) return;
        blur2_row(spIn, spOut + (size_t)m * CP, nA_sp, nB_sp, m);
    }
}

// phase 2: bilateral double-blur + spatial single-blur
__global__ void blurP2_k(const __half2* __restrict__ biIn, __half2* __restrict__ biOut,
                         const int* __restrict__ nA_bi, const int* __restrict__ nB_bi, int Mbi,
                         const __half2* __restrict__ spIn, __half2* __restrict__ spOut,
                         const int* __restrict__ nA_sp, int Msp) {
    int t = blockIdx.x * blockDim.x + threadIdx.x;
    if (t <= Mbi) {
        blur2_row(biIn, biOut + (size_t)t * CP, nA_bi, nB_bi, t);
    } else {
        int m = t - (Mbi + 1);
        if (m > Msp) return;
        blur1_row(spIn, spOut + (size_t)m * CP, nA_sp, m);
    }
}

// phase 3: bilateral double-blur only
__global__ void blurP3_k(const __half2* __restrict__ biIn, __half2* __restrict__ biOut,
                         const int* __restrict__ nA_bi, const int* __restrict__ nB_bi, int Mbi) {
    int t = blockIdx.x * blockDim.x + threadIdx.x;
    if (t > Mbi) return;
    blur2_row(biIn, biOut + (size_t)t * CP, nA_bi, nB_bi, t);
}

// fused: slice bilateral + slice spatial + softmax update.
__global__ void slice_update_k(const __half2* __restrict__ uh,
                               const int* __restrict__ os_bi, const float* __restrict__ ws_bi,
                               const __half2* __restrict__ vbi, const float* __restrict__ nrm_bi,
                               const int* __restrict__ os_sp, const float* __restrict__ ws_sp,
                               const __half2* __restrict__ vsp, const float* __restrict__ nrm_sp,
                               float* __restrict__ Q, __half2* __restrict__ Qh,
                               int N, float abi, float asp, int final_it) {
    int n = blockIdx.x * blockDim.x + threadIdx.x;
    if (n >= N) return;
    float acc[2 * CP];
#pragma unroll
    for (int i = 0; i < 2 * CP; i++) acc[i] = 0.f;
    for (int j = 0; j < 6; j++) {
        float w = ws_bi[(size_t)n * 6 + j];
        const __half2* vp = vbi + (size_t)os_bi[(size_t)n * 6 + j] * CP;
#pragma unroll
        for (int i = 0; i < CP; i++) {
            float2 f = __half22float2(vp[i]);
            acc[2 * i]     += w * f.x;
            acc[2 * i + 1] += w * f.y;
        }
    }
    float sb = 10.f * abi * nrm_bi[n];
#pragma unroll
    for (int i = 0; i < 2 * CP; i++) acc[i] *= sb;
    float ss = 3.f * asp * nrm_sp[n];
    for (int j = 0; j < 3; j++) {
        float w = ss * ws_sp[(size_t)n * 3 + j];
        const __half2* vp = vsp + (size_t)os_sp[(size_t)n * 3 + j] * CP;
#pragma unroll
        for (int i = 0; i < CP; i++) {
            float2 f = __half22float2(vp[i]);
            acc[2 * i]     += w * f.x;
            acc[2 * i + 1] += w * f.y;
        }
    }
    const __half2* uhp = uh + (size_t)n * CP;
#pragma unroll
    for (int i = 0; i < CP; i++) {
        float2 uu = __half22float2(uhp[i]);
        acc[2 * i]     -= uu.x;
        acc[2 * i + 1] -= uu.y;
    }
    float mx = -1e30f;
#pragma unroll
    for (int c = 0; c < NC; c++) mx = fmaxf(mx, acc[c]);
    float s = 0.f;
#pragma unroll
    for (int c = 0; c < NC; c++) { acc[c] = __expf(acc[c] - mx); s += acc[c]; }
    float inv = 1.f / s;
#pragma unroll
    for (int c = 0; c < NC; c++) acc[c] *= inv;
#pragma unroll
    for (int c = NC; c < 2 * CP; c++) acc[c] = 0.f;
    if (final_it) {
        float* qp = Q + (size_t)n * NC;
#pragma unroll
        for (int c = 0; c < NC; c++) qp[c] = acc[c];
    } else {
        __half2* hp = Qh + (size_t)n * CP;
#pragma unroll
        for (int i = 0; i < CP; i++) hp[i] = __floats2half2_rn(acc[2 * i], acc[2 * i + 1]);
    }
}

extern "C" void kernel_launch(void* const* d_in, const int* in_sizes, int n_in,
                              void* d_out, int out_size, void* d_ws, size_t ws_size,
                              hipStream_t stream) {
    const float* unary  = (const float*)d_in[0];
    const float* ws_bi  = (const float*)d_in[1];
    const float* ws_sp  = (const float*)d_in[2];
    const int*   os_bi  = (const int*)d_in[3];
    const int*   os_sp  = (const int*)d_in[4];
    const int*   nbr_bi = (const int*)d_in[5];
    const int*   nbr_sp = (const int*)d_in[6];
    float* Q = (float*)d_out;

    const int N = NPIX, Kbi = 6, Ksp = 3;
    const int Mbi = in_sizes[5] / (Kbi * 2);
    const int Msp = in_sizes[6] / (Ksp * 2);
    const int NKbi = N * Kbi, NKsp = N * Ksp;
    const float alpha_bi = 32.f / 33.f;
    const float alpha_sp = 0.8f;

    // ---- workspace layout (4-byte units) ----
    char* basec = (char*)d_ws;
    size_t off4 = 0;
    auto allocf = [&](size_t nf) { float* p = (float*)basec + off4; off4 += (nf + 3) & ~(size_t)3; return p; };
    auto alloci = [&](size_t ni) { int* p = (int*)basec + off4; off4 += (ni + 3) & ~(size_t)3; return p; };
    auto alloch2 = [&](size_t nh2) { __half2* p = (__half2*)((float*)basec + off4); off4 += (nh2 + 3) & ~(size_t)3; return p; };
    auto alloci2 = [&](size_t ni2) { int2* p = (int2*)((float*)basec + off4); off4 += 2 * ni2; return p; };

    float*   nrm_bi = allocf(N);
    float*   nrm_sp = allocf(N);
    __half2* Qh     = alloch2((size_t)N * CP);
    __half2* uh     = alloch2((size_t)N * CP);
    int2*    pE_bi  = alloci2(NKbi);
    int*     off_bi = alloci(Mbi + 2);
    int2*    pE_sp  = alloci2(NKsp);
    int*     off_sp = alloci(Msp + 2);
    int*     bsumA  = alloci(4096);
    int*     bsumB  = alloci(4096);
    __half2* vbiA   = alloch2((size_t)(Mbi + 1) * CP);
    __half2* vbiB   = alloch2((size_t)(Mbi + 1) * CP);
    __half2* vspA   = alloch2((size_t)(Msp + 1) * CP);
    __half2* vspB   = alloch2((size_t)(Msp + 1) * CP);
    // cnt/rnk are only live during the CSR build (before splat1d), so they alias
    // the vbiA region (first use of vbiA is nv_biA in splat1d, after scatter2).
    int* cnt_bi = (int*)vbiA;
    int* cnt_sp = cnt_bi + (Mbi + 1);
    int* rnk_bi = cnt_sp + (Msp + 1);
    int* rnk_sp = rnk_bi + NKbi;
    // f32 norm-lattice buffers reuse the (not-yet-live) f16 value regions
    float* nv_biA = (float*)vbiA;
    float* nv_biB = (float*)vbiB;
    float* nv_spA = (float*)vspA;
    float* nv_spB = (float*)vspB;

    const int B = 256;
    const int nb_bi = cdiv_l(Mbi + 1, SCAN_CHUNK);
    const int nb_sp = cdiv_l(Msp + 1, SCAN_CHUNK);
    const size_t cnt_span = ((size_t)(Mbi + 1) + (Msp + 1)) * sizeof(int);
    const int rows2 = (Mbi + 1) + (Msp + 1);

    // ---- CSR build (both lattices), j-major, rank-trick (atomic-free scatter) ----
    hipMemsetAsync(cnt_bi, 0, cnt_span, stream);
    histrank2_k<<<cdiv_l((long)NKbi + NKsp, B), B, 0, stream>>>(
        os_bi, cnt_bi, rnk_bi, NKbi, Kbi, os_sp, cnt_sp, rnk_sp, NKsp, Ksp);
    scan1d_k<<<nb_bi + nb_sp, SCAN_T, 0, stream>>>(cnt_bi, bsumA, Mbi + 1, nb_bi,
                                                   cnt_sp, bsumB, Msp + 1);
    scan2d_k<<<2, SCAN_T, 0, stream>>>(bsumA, nb_bi, off_bi, Mbi + 1,
                                       bsumB, nb_sp, off_sp, Msp + 1);
    scan3d_k<<<nb_bi + nb_sp, SCAN_T, 0, stream>>>(cnt_bi, bsumA, off_bi, Mbi + 1, nb_bi,
                                                   cnt_sp, bsumB, off_sp, Msp + 1);
    scatter2_k<<<cdiv_l((long)NKbi + NKsp, B), B, 0, stream>>>(
        os_bi, ws_bi, off_bi, rnk_bi, pE_bi, NKbi, Kbi,
        os_sp, ws_sp, off_sp, rnk_sp, pE_sp, NKsp, Ksp);

    // ---- normalization lattices (C=1, f32), dual-range ----
    splat1d_k<<<cdiv_l(rows2, B), B, 0, stream>>>(pE_bi, off_bi, nv_biA, Mbi,
                                                  pE_sp, off_sp, nv_spA, Msp);
    {
        float* sb = nv_biA; float* db = nv_biB;
        float* sp = nv_spA; float* dp = nv_spB;
        for (int j = 0; j < 3; j++) {   // dual sweeps (bi dir j, sp dir j)
            blur1d_k<<<cdiv_l(rows2, B), B, 0, stream>>>(
                sb, db, nbr_bi + (size_t)j * Mbi * 2, Mbi,
                sp, dp, nbr_sp + (size_t)j * Msp * 2, Msp);
            float* t = sb; sb = db; db = t;
            t = sp; sp = dp; dp = t;
        }
        for (int j = 3; j < 6; j++) {   // bilateral-only sweeps
            blur1d_k<<<cdiv_l(Mbi + 1, B), B, 0, stream>>>(
                sb, db, nbr_bi + (size_t)j * Mbi * 2, Mbi,
                nullptr, nullptr, nullptr, 0);
            float* t = sb; sb = db; db = t;
        }
        prep_k<<<cdiv_l(3L * N, B), B, 0, stream>>>(
            unary, os_bi, ws_bi, sb, nrm_bi, alpha_bi,
            os_sp, ws_sp, sp, nrm_sp, alpha_sp, Qh, uh, N);
    }

    // ---- fold nrm into packed entry weights ----
    wn2_k<<<cdiv_l((long)NKbi + NKsp, B), B, 0, stream>>>(pE_bi, nrm_bi, NKbi, pE_sp, nrm_sp, NKsp);

    // ---- mean-field iterations ----
    for (int it = 0; it < 5; it++) {
        splatH2_k<<<cdiv_l(rows2, B), B, 0, stream>>>(
            Qh, pE_bi, off_bi, vbiA, Mbi,
            pE_sp, off_sp, vspA, Msp);
        blurP1_k<<<cdiv_l(rows2, B), B, 0, stream>>>(
            vbiA, vbiB, nbr_bi + (size_t)0 * Mbi * 2, nbr_bi + (size_t)1 * Mbi * 2, Mbi,
            vspA, vspB, nbr_sp + (size_t)0 * Msp * 2, nbr_sp + (size_t)1 * Msp * 2, Msp);
        blurP2_k<<<cdiv_l(rows2, B), B, 0, stream>>>(
            vbiB, vbiA, nbr_bi + (size_t)2 * Mbi * 2, nbr_bi + (size_t)3 * Mbi * 2, Mbi,
            vspB, vspA, nbr_sp + (size_t)2 * Msp * 2, Msp);
        blurP3_k<<<cdiv_l(Mbi + 1, B), B, 0, stream>>>(
            vbiA, vbiB, nbr_bi + (size_t)4 * Mbi * 2, nbr_bi + (size_t)5 * Mbi * 2, Mbi);
        slice_update_k<<<cdiv_l(N, B), B, 0, stream>>>(
            uh, os_bi, ws_bi, vbiB, nrm_bi, os_sp, ws_sp, vspA, nrm_sp,
            Q, Qh, N, alpha_bi, alpha_sp, it == 4 ? 1 : 0);
    }
}